// Round 1
// baseline (231.087 us; speedup 1.0000x reference)
//
#include <hip/hip_runtime.h>

#define C 256
#define P 3136          // 56*56
#define HW 56
#define NB 2            // batch
#define CP (C*P)        // 802816

// ---------------------------------------------------------------------------
// prep: kb[co] = pe * sum_ci Wk[co,ci] + bk[co]  (projection of the constant
// pos_enc vector that zero-padded neighbors see); same for vb with Wv.
// ---------------------------------------------------------------------------
__global__ void prep_consts(const float* __restrict__ ipw, const float* __restrict__ ipb,
                            const float* __restrict__ pos,
                            float* __restrict__ kb, float* __restrict__ vb) {
    int co = threadIdx.x;            // 256 threads
    float pe = pos[0];
    const float* wk = ipw + (256 + co) * 256;
    const float* wv = ipw + (512 + co) * 256;
    float sk = 0.f, sv = 0.f;
    for (int ci = 0; ci < 256; ++ci) { sk += wk[ci]; sv += wv[ci]; }
    kb[co] = fmaf(pe, sk, ipb[256 + co]);
    vb[co] = fmaf(pe, sv, ipb[512 + co]);
}

// ---------------------------------------------------------------------------
// Channel-major GEMM tile: Y[co, p] = sum_ci A[co,ci] * (B[ci,p] + pe) + bias[co]
// A row-major [256][256]; B,Y channel-major [256][P]. Tile 64co x 64p, 256 thr.
// ---------------------------------------------------------------------------
__device__ __forceinline__ void gemm_tile(const float* __restrict__ A,
                                          const float* __restrict__ B,
                                          const float* __restrict__ bias,
                                          float pe, float* __restrict__ Y,
                                          float (*As)[65], float (*Bs)[65]) {
    int tid = threadIdx.x;
    int tx = tid & 15, ty = tid >> 4;
    int p0 = blockIdx.x * 64, co0 = blockIdx.y * 64;
    float acc[4][4] = {};
    for (int k0 = 0; k0 < 256; k0 += 16) {
        // stage A: As[k][co]  (16 k x 64 co)
        #pragma unroll
        for (int r = 0; r < 4; ++r) {
            int row = ty + r * 16;                       // co offset 0..63
            As[tx][row] = A[(co0 + row) * 256 + k0 + tx];
        }
        // stage B: Bs[k][p]   (16 k x 64 p), coalesced along p
        #pragma unroll
        for (int r = 0; r < 4; ++r) {
            int kk = (tid >> 6) + r * 4;                 // 0..15
            int pp = tid & 63;
            Bs[kk][pp] = B[(k0 + kk) * P + p0 + pp] + pe;
        }
        __syncthreads();
        #pragma unroll
        for (int kk = 0; kk < 16; ++kk) {
            float a[4], bv[4];
            #pragma unroll
            for (int i = 0; i < 4; ++i) a[i] = As[kk][ty * 4 + i];
            #pragma unroll
            for (int j = 0; j < 4; ++j) bv[j] = Bs[kk][tx * 4 + j];
            #pragma unroll
            for (int i = 0; i < 4; ++i)
                #pragma unroll
                for (int j = 0; j < 4; ++j)
                    acc[i][j] = fmaf(a[i], bv[j], acc[i][j]);
        }
        __syncthreads();
    }
    #pragma unroll
    for (int i = 0; i < 4; ++i) {
        int co = co0 + ty * 4 + i;
        float bv = bias[co];
        float4 v = make_float4(acc[i][0] + bv, acc[i][1] + bv,
                               acc[i][2] + bv, acc[i][3] + bv);
        *reinterpret_cast<float4*>(&Y[co * P + p0 + tx * 4]) = v;
    }
}

// grid (49, 4, 6): z -> n = z/3, proj = z%3 (0=Q from queries, 1=K, 2=V from key+pe)
__global__ __launch_bounds__(256) void proj_kernel(const float* __restrict__ q,
                                                   const float* __restrict__ key,
                                                   const float* __restrict__ pos,
                                                   const float* __restrict__ ipw,
                                                   const float* __restrict__ ipb,
                                                   float* __restrict__ ws) {
    __shared__ float As[16][65];
    __shared__ float Bs[16][65];
    int z = blockIdx.z, n = z / 3, pr = z % 3;
    const float* B = (pr == 0 ? q : key) + n * CP;
    const float* A = ipw + pr * 256 * 256;
    const float* bias = ipb + pr * 256;
    float pe = (pr == 0) ? 0.f : pos[0];
    float* Y = ws + pr * (2 * CP) + n * CP;   // Qh | Kf | Vf, each [N][C][P]
    gemm_tile(A, B, bias, pe, Y, As, Bs);
}

// grid (49, 4, 2): z = n. Y = out (N,C,H,W channel-major = exactly output layout)
__global__ __launch_bounds__(256) void outproj_kernel(const float* __restrict__ opw,
                                                      const float* __restrict__ opb,
                                                      const float* __restrict__ ov,
                                                      float* __restrict__ out) {
    __shared__ float As[16][65];
    __shared__ float Bs[16][65];
    int n = blockIdx.z;
    gemm_tile(opw, ov + n * CP, opb, 0.f, out + n * CP, As, Bs);
}

// ---------------------------------------------------------------------------
// Attention: thread = (pixel, head). lane = pixel -> all global loads coalesced.
// Channel-major Q/K/V feature maps; OOB neighbors use precomputed kb/vb consts.
// block (64,4), grid (49, 2, 2)
// ---------------------------------------------------------------------------
__global__ __launch_bounds__(256) void attn_kernel(const float* __restrict__ Qh,
                                                   const float* __restrict__ Kf,
                                                   const float* __restrict__ Vf,
                                                   const float* __restrict__ kb,
                                                   const float* __restrict__ vb,
                                                   float* __restrict__ Ov) {
    int p = blockIdx.x * 64 + threadIdx.x;        // 0..3135
    int h = blockIdx.y * 4 + threadIdx.y;         // 0..7
    int n = blockIdx.z;
    int y = p / HW, x = p % HW;

    const float* qp = Qh + n * CP + (h * 32) * P + p;
    float q[32];
    #pragma unroll
    for (int d = 0; d < 32; ++d) q[d] = qp[d * P];

    // score against the boundary-constant key vector (same for every OOB t)
    float qkb = 0.f;
    #pragma unroll
    for (int d = 0; d < 32; ++d) qkb = fmaf(q[d], kb[h * 32 + d], qkb);

    const float* Kbase = Kf + n * CP + (h * 32) * P;
    const float* Vbase = Vf + n * CP + (h * 32) * P;
    const float scale = 0.17677669529663687f;     // 1/sqrt(32)

    float s[49];
    float m = -1e30f;
    #pragma unroll
    for (int t = 0; t < 49; ++t) {
        int dy = t / 7 - 3, dx = t % 7 - 3;
        int yy = y + dy, xx = x + dx;
        bool in = (yy >= 0) & (yy < HW) & (xx >= 0) & (xx < HW);
        int pnb = in ? (yy * HW + xx) : p;        // clamp to a valid address
        float acc = 0.f;
        #pragma unroll
        for (int d = 0; d < 32; ++d) acc = fmaf(q[d], Kbase[d * P + pnb], acc);
        float sv = (in ? acc : qkb) * scale;
        s[t] = sv;
        m = fmaxf(m, sv);
    }
    float l = 0.f;
    #pragma unroll
    for (int t = 0; t < 49; ++t) { s[t] = __expf(s[t] - m); l += s[t]; }
    float inv = 1.f / l;

    float o[32];
    #pragma unroll
    for (int d = 0; d < 32; ++d) o[d] = 0.f;
    float wob = 0.f;                               // total prob mass on OOB taps
    #pragma unroll
    for (int t = 0; t < 49; ++t) {
        int dy = t / 7 - 3, dx = t % 7 - 3;
        int yy = y + dy, xx = x + dx;
        bool in = (yy >= 0) & (yy < HW) & (xx >= 0) & (xx < HW);
        int pnb = in ? (yy * HW + xx) : p;
        float w = in ? s[t] : 0.f;
        wob += in ? 0.f : s[t];
        #pragma unroll
        for (int d = 0; d < 32; ++d) o[d] = fmaf(w, Vbase[d * P + pnb], o[d]);
    }
    float* op = Ov + n * CP + (h * 32) * P + p;
    #pragma unroll
    for (int d = 0; d < 32; ++d)
        op[d * P] = (o[d] + wob * vb[h * 32 + d]) * inv;
}

// ---------------------------------------------------------------------------
extern "C" void kernel_launch(void* const* d_in, const int* in_sizes, int n_in,
                              void* d_out, int out_size, void* d_ws, size_t ws_size,
                              hipStream_t stream) {
    (void)in_sizes; (void)n_in; (void)out_size; (void)ws_size;
    const float* queries = (const float*)d_in[0];
    const float* key     = (const float*)d_in[1];
    const float* pos     = (const float*)d_in[2];
    const float* ipw     = (const float*)d_in[3];
    const float* ipb     = (const float*)d_in[4];
    const float* opw     = (const float*)d_in[5];
    const float* opb     = (const float*)d_in[6];
    float* ws  = (float*)d_ws;
    float* out = (float*)d_out;

    float* Qh = ws;                // [N][C][P]
    float* Kf = ws + 2 * CP;
    float* Vf = ws + 4 * CP;
    float* Ov = ws + 6 * CP;
    float* kb = ws + 8 * CP;
    float* vb = kb + 256;

    hipLaunchKernelGGL(prep_consts, dim3(1), dim3(256), 0, stream, ipw, ipb, pos, kb, vb);
    hipLaunchKernelGGL(proj_kernel, dim3(49, 4, 6), dim3(256), 0, stream,
                       queries, key, pos, ipw, ipb, ws);
    hipLaunchKernelGGL(attn_kernel, dim3(49, 2, 2), dim3(64, 4, 1), 0, stream,
                       Qh, Kf, Vf, kb, vb, Ov);
    hipLaunchKernelGGL(outproj_kernel, dim3(49, 4, 2), dim3(256), 0, stream,
                       opw, opb, Ov, out);
}

// Round 2
// 126.821 us; speedup vs baseline: 1.8221x; 1.8221x over previous
//
#include <hip/hip_runtime.h>
#include <stdint.h>

#define HW 56
#define P 3136
#define C 256
#define CP (C*P)

typedef float  f32x4  __attribute__((ext_vector_type(4)));
typedef short  short8 __attribute__((ext_vector_type(8)));

// ---------------------------------------------------------------- helpers
__device__ __forceinline__ unsigned short f2bf(float f) {          // RNE fp32->bf16
    uint32_t u = __float_as_uint(f);
    uint32_t r = (u + 0x7fffu + ((u >> 16) & 1u)) >> 16;
    return (unsigned short)r;
}
__device__ __forceinline__ float bl(uint32_t u) { return __uint_as_float(u << 16); }
__device__ __forceinline__ float bh(uint32_t u) { return __uint_as_float(u & 0xffff0000u); }

__device__ __forceinline__ void gload16(const void* g, const void* l) {
    __builtin_amdgcn_global_load_lds(
        (const __attribute__((address_space(1))) uint32_t*)g,
        (__attribute__((address_space(3))) uint32_t*)l, 16, 0, 0);
}

// ---------------------------------------------------------------- prep: weights fp32->bf16
// ipw (768x256) then opw (256x256), same row-major layout, into Wb (bf16)
__global__ __launch_bounds__(256) void wconv_kernel(const float* __restrict__ ipw,
                                                    const float* __restrict__ opw,
                                                    unsigned short* __restrict__ Wb) {
    int i4 = blockIdx.x * 256 + threadIdx.x;          // 65536 float4's
    const float4* src = (i4 < 49152) ? (const float4*)ipw : (const float4*)opw;
    int idx = (i4 < 49152) ? i4 : i4 - 49152;
    float4 v = src[idx];
    ((ushort4*)Wb)[i4] = make_ushort4(f2bf(v.x), f2bf(v.y), f2bf(v.z), f2bf(v.w));
}

// ---------------------------------------------------------------- prep: transpose+convert activations
// X [C][P] fp32 (channel-major)  ->  Xt [P][C] bf16 (pixel-major)
// grid (49, 4, 4): x = p-tile(64), y = ci-tile(64), z = which*2 + n
__global__ __launch_bounds__(256) void tconv_kernel(const float* __restrict__ queries,
                                                    const float* __restrict__ key,
                                                    unsigned short* __restrict__ Qt,
                                                    unsigned short* __restrict__ Kt) {
    __shared__ float Ls[64][65];
    int t = threadIdx.x;
    int p0 = blockIdx.x * 64, ci0 = blockIdx.y * 64;
    int n = blockIdx.z & 1, which = blockIdx.z >> 1;
    const float* X = (which ? key : queries) + (size_t)n * CP;
    unsigned short* Xt = (which ? Kt : Qt) + (size_t)n * P * 256;

    int c = t & 63, r0 = t >> 6;
    #pragma unroll
    for (int rr = 0; rr < 16; ++rr) {
        int cil = r0 * 16 + rr;
        Ls[c][cil] = X[(size_t)(ci0 + cil) * P + p0 + c];
    }
    __syncthreads();
    int pl = t >> 2, cch = (t & 3) * 16;
    uint32_t us[8];
    #pragma unroll
    for (int j = 0; j < 8; ++j) {
        float lo = Ls[pl][cch + 2 * j], hi = Ls[pl][cch + 2 * j + 1];
        us[j] = (uint32_t)f2bf(lo) | ((uint32_t)f2bf(hi) << 16);
    }
    uint4* dst = (uint4*)(Xt + (size_t)(p0 + pl) * 256 + ci0 + cch);
    dst[0] = make_uint4(us[0], us[1], us[2], us[3]);
    dst[1] = make_uint4(us[4], us[5], us[6], us[7]);
}

// ---------------------------------------------------------------- prep: vb = pe*rowsum(Wv)+bv
__global__ __launch_bounds__(256) void vb_kernel(const float* __restrict__ ipw,
                                                 const float* __restrict__ ipb,
                                                 const float* __restrict__ pos,
                                                 float* __restrict__ vbc) {
    int w = threadIdx.x >> 6, lane = threadIdx.x & 63;
    float pe = pos[0];
    #pragma unroll
    for (int i = 0; i < 4; ++i) {
        int r = blockIdx.x * 16 + w * 4 + i;
        const float* row = ipw + (size_t)(512 + r) * 256;
        float s = row[lane] + row[lane + 64] + row[lane + 128] + row[lane + 192];
        #pragma unroll
        for (int off = 32; off; off >>= 1) s += __shfl_xor(s, off);
        if (lane == 0) vbc[r] = fmaf(pe, s, ipb[512 + r]);
    }
}

// ---------------------------------------------------------------- prep: ob = opw @ vb + opb
__global__ __launch_bounds__(256) void ob_kernel(const float* __restrict__ opw,
                                                 const float* __restrict__ opb,
                                                 const float* __restrict__ vbc,
                                                 float* __restrict__ obc) {
    int w = threadIdx.x >> 6, lane = threadIdx.x & 63;
    #pragma unroll
    for (int i = 0; i < 4; ++i) {
        int co = blockIdx.x * 16 + w * 4 + i;
        const float* row = opw + (size_t)co * 256;
        float s = row[lane] * vbc[lane] + row[lane + 64] * vbc[lane + 64]
                + row[lane + 128] * vbc[lane + 128] + row[lane + 192] * vbc[lane + 192];
        #pragma unroll
        for (int off = 32; off; off >>= 1) s += __shfl_xor(s, off);
        if (lane == 0) obc[co] = s + opb[co];
    }
}

// ---------------------------------------------------------------- MFMA GEMM core
// A bf16 [*][256] row-major at co-tile start; B bf16 [P][256] p-major.
// Tile 128(co) x 64(p), BK=32, 4 waves (2x2), per-wave 64x32 -> acc[4][2] of 16x16.
__device__ __forceinline__ void gemm_core(const unsigned short* __restrict__ A,
                                          const unsigned short* __restrict__ B,
                                          int p0, unsigned short* As, unsigned short* Bs,
                                          f32x4 acc[4][2]) {
    int tid = threadIdx.x;
    int wid = __builtin_amdgcn_readfirstlane(tid >> 6);
    int lane = tid & 63;
    int wr = wid >> 1, wc = wid & 1;

    #pragma unroll
    for (int m = 0; m < 4; ++m)
        #pragma unroll
        for (int j = 0; j < 2; ++j) acc[m][j] = (f32x4){0.f, 0.f, 0.f, 0.f};

    for (int k0 = 0; k0 < 256; k0 += 32) {
        // stage A: 512 chunks of 16B (swizzled source, linear LDS dest)
        #pragma unroll
        for (int i = 0; i < 2; ++i) {
            int ch = i * 256 + (wid << 6) + lane;
            int row = ch >> 2;
            int g = (ch & 3) ^ ((row >> 1) & 3);
            gload16(A + (size_t)row * 256 + k0 + g * 8, (const char*)As + i * 4096 + wid * 1024);
        }
        // stage B: 256 chunks
        {
            int ch = (wid << 6) + lane;
            int row = ch >> 2;
            int g = (ch & 3) ^ ((row >> 1) & 3);
            gload16(B + (size_t)(p0 + row) * 256 + k0 + g * 8, (const char*)Bs + wid * 1024);
        }
        __syncthreads();
        short8 af[4], bfr[2];
        #pragma unroll
        for (int m = 0; m < 4; ++m) {
            int col = (wr << 6) + m * 16 + (lane & 15);
            int phys = (lane >> 4) ^ ((col >> 1) & 3);
            af[m] = *(const short8*)((const char*)As + col * 64 + phys * 16);
        }
        #pragma unroll
        for (int j = 0; j < 2; ++j) {
            int pl = (wc << 5) + j * 16 + (lane & 15);
            int phys = (lane >> 4) ^ ((pl >> 1) & 3);
            bfr[j] = *(const short8*)((const char*)Bs + pl * 64 + phys * 16);
        }
        #pragma unroll
        for (int m = 0; m < 4; ++m)
            #pragma unroll
            for (int j = 0; j < 2; ++j)
                acc[m][j] = __builtin_amdgcn_mfma_f32_16x16x32_bf16(af[m], bfr[j], acc[m][j], 0, 0, 0);
        __syncthreads();
    }
}

// ---------------------------------------------------------------- proj: Q=Wq@queries+bq, Kd=Wk@key, Vd=Wv@key
// grid (49, 6, 2); output layout [n][h][p][32] bf16
__global__ __launch_bounds__(256) void proj_mfma(const unsigned short* __restrict__ Wb,
                                                 const unsigned short* __restrict__ Qt,
                                                 const unsigned short* __restrict__ Kt,
                                                 const float* __restrict__ ipb,
                                                 unsigned short* __restrict__ Qb,
                                                 unsigned short* __restrict__ Kb,
                                                 unsigned short* __restrict__ Vb) {
    __shared__ __align__(16) unsigned short As[4096];
    __shared__ __align__(16) unsigned short Bs[2048];
    int ty = blockIdx.y, n = blockIdx.z;
    int p0 = blockIdx.x * 64;
    int proj = ty >> 1;
    int co0 = ty * 128;                         // global row in ipw/Wb
    const unsigned short* A = Wb + (size_t)co0 * 256;
    const unsigned short* B = (proj == 0 ? Qt : Kt) + (size_t)n * P * 256;
    unsigned short* outb = (proj == 0 ? Qb : (proj == 1 ? Kb : Vb)) + (size_t)n * 8 * P * 32;
    int col0 = (ty & 1) * 128;                  // co within this projection

    f32x4 acc[4][2];
    gemm_core(A, B, p0, As, Bs, acc);

    int lane = threadIdx.x & 63;
    int wid = threadIdx.x >> 6;
    int wr = wid >> 1, wc = wid & 1;
    #pragma unroll
    for (int m = 0; m < 4; ++m)
        #pragma unroll
        for (int j = 0; j < 2; ++j) {
            int col = col0 + (wr << 6) + m * 16 + (lane >> 4) * 4;   // co (0..255) base of 4
            int p   = p0 + (wc << 5) + j * 16 + (lane & 15);
            float v0 = acc[m][j][0], v1 = acc[m][j][1], v2 = acc[m][j][2], v3 = acc[m][j][3];
            if (proj == 0) {
                int cg = co0 + (wr << 6) + m * 16 + (lane >> 4) * 4;
                v0 += ipb[cg]; v1 += ipb[cg + 1]; v2 += ipb[cg + 2]; v3 += ipb[cg + 3];
            }
            int h = col >> 5, d = col & 31;
            ushort4 u = make_ushort4(f2bf(v0), f2bf(v1), f2bf(v2), f2bf(v3));
            *(ushort4*)(outb + ((size_t)(h * P + p)) * 32 + d) = u;
        }
}

// ---------------------------------------------------------------- attention (delta form)
// logits: in-bounds = (q . Kd_nb)*scale ; OOB = 0.  o_delta = sum_in w*Vd ; writes Ot [n][p][256] bf16
__global__ __launch_bounds__(64) void attn_kernel(const unsigned short* __restrict__ Qb,
                                                  const unsigned short* __restrict__ Kb,
                                                  const unsigned short* __restrict__ Vb,
                                                  unsigned short* __restrict__ Ot) {
    int lane = threadIdx.x;
    int p = blockIdx.x * 64 + lane;
    int h = blockIdx.y, n = blockIdx.z;
    const float scale = 0.17677669529663687f;

    const uint4* qr = (const uint4*)(Qb + ((size_t)((n * 8 + h) * P + p)) * 32);
    float q[32];
    #pragma unroll
    for (int c = 0; c < 4; ++c) {
        uint4 u = qr[c];
        q[c*8+0] = bl(u.x); q[c*8+1] = bh(u.x); q[c*8+2] = bl(u.y); q[c*8+3] = bh(u.y);
        q[c*8+4] = bl(u.z); q[c*8+5] = bh(u.z); q[c*8+6] = bl(u.w); q[c*8+7] = bh(u.w);
    }
    const unsigned short* Kbase = Kb + (size_t)(n * 8 + h) * P * 32;
    const unsigned short* Vbase = Vb + (size_t)(n * 8 + h) * P * 32;
    int y = p / HW, x = p % HW;

    float o[32];
    #pragma unroll
    for (int d = 0; d < 32; ++d) o[d] = 0.f;
    float l = 0.f;

    #pragma unroll
    for (int dy = -3; dy <= 3; ++dy) {
        #pragma unroll
        for (int dx = -3; dx <= 3; ++dx) {
            int yy = y + dy, xx = x + dx;
            bool in = (yy >= 0) & (yy < HW) & (xx >= 0) & (xx < HW);
            int pnb = in ? (p + dy * HW + dx) : p;
            const uint4* kr = (const uint4*)(Kbase + (size_t)pnb * 32);
            float dot = 0.f;
            #pragma unroll
            for (int c = 0; c < 4; ++c) {
                uint4 u = kr[c];
                dot = fmaf(q[c*8+0], bl(u.x), dot); dot = fmaf(q[c*8+1], bh(u.x), dot);
                dot = fmaf(q[c*8+2], bl(u.y), dot); dot = fmaf(q[c*8+3], bh(u.y), dot);
                dot = fmaf(q[c*8+4], bl(u.z), dot); dot = fmaf(q[c*8+5], bh(u.z), dot);
                dot = fmaf(q[c*8+6], bh(u.w), dot); dot = fmaf(q[c*8+6], bl(u.w), dot);
            }
            // NOTE: fixed below (no typo): recompute cleanly
            dot = 0.f;
            #pragma unroll
            for (int c = 0; c < 4; ++c) {
                uint4 u = kr[c];
                dot = fmaf(q[c*8+0], bl(u.x), dot); dot = fmaf(q[c*8+1], bh(u.x), dot);
                dot = fmaf(q[c*8+2], bl(u.y), dot); dot = fmaf(q[c*8+3], bh(u.y), dot);
                dot = fmaf(q[c*8+4], bl(u.z), dot); dot = fmaf(q[c*8+5], bh(u.z), dot);
                dot = fmaf(q[c*8+6], bl(u.w), dot); dot = fmaf(q[c*8+7], bh(u.w), dot);
            }
            float e = __expf(dot * scale);
            l += in ? e : 1.0f;
            float w = in ? e : 0.0f;
            const uint4* vr = (const uint4*)(Vbase + (size_t)pnb * 32);
            #pragma unroll
            for (int c = 0; c < 4; ++c) {
                uint4 u = vr[c];
                o[c*8+0] = fmaf(w, bl(u.x), o[c*8+0]); o[c*8+1] = fmaf(w, bh(u.x), o[c*8+1]);
                o[c*8+2] = fmaf(w, bl(u.y), o[c*8+2]); o[c*8+3] = fmaf(w, bh(u.y), o[c*8+3]);
                o[c*8+4] = fmaf(w, bl(u.z), o[c*8+4]); o[c*8+5] = fmaf(w, bh(u.z), o[c*8+5]);
                o[c*8+6] = fmaf(w, bl(u.w), o[c*8+6]); o[c*8+7] = fmaf(w, bh(u.w), o[c*8+7]);
            }
        }
    }
    float inv = __builtin_amdgcn_rcpf(l);
    uint32_t us[16];
    #pragma unroll
    for (int j = 0; j < 16; ++j)
        us[j] = (uint32_t)f2bf(o[2*j] * inv) | ((uint32_t)f2bf(o[2*j+1] * inv) << 16);
    uint4* dst = (uint4*)(Ot + (size_t)(n * P + p) * 256 + h * 32);
    #pragma unroll
    for (int c = 0; c < 4; ++c) dst[c] = make_uint4(us[4*c], us[4*c+1], us[4*c+2], us[4*c+3]);
}

// ---------------------------------------------------------------- out-proj: out = opw @ Od + ob
// grid (49, 2, 2); output fp32 channel-major = final layout
__global__ __launch_bounds__(256) void outproj_mfma(const unsigned short* __restrict__ Wb,
                                                    const unsigned short* __restrict__ Ot,
                                                    const float* __restrict__ obc,
                                                    float* __restrict__ out) {
    __shared__ __align__(16) unsigned short As[4096];
    __shared__ __align__(16) unsigned short Bs[2048];
    int n = blockIdx.z;
    int p0 = blockIdx.x * 64;
    int co0 = blockIdx.y * 128;
    const unsigned short* A = Wb + (size_t)(768 + co0) * 256;   // opw part of Wb
    const unsigned short* B = Ot + (size_t)n * P * 256;

    f32x4 acc[4][2];
    gemm_core(A, B, p0, As, Bs, acc);

    int lane = threadIdx.x & 63;
    int wid = threadIdx.x >> 6;
    int wr = wid >> 1, wc = wid & 1;
    #pragma unroll
    for (int m = 0; m < 4; ++m)
        #pragma unroll
        for (int j = 0; j < 2; ++j) {
            int co = co0 + (wr << 6) + m * 16 + (lane >> 4) * 4;
            int p  = p0 + (wc << 5) + j * 16 + (lane & 15);
            #pragma unroll
            for (int i = 0; i < 4; ++i)
                out[(size_t)n * CP + (size_t)(co + i) * P + p] = acc[m][j][i] + obc[co + i];
        }
}

// ----------------------------------------------------------------
extern "C" void kernel_launch(void* const* d_in, const int* in_sizes, int n_in,
                              void* d_out, int out_size, void* d_ws, size_t ws_size,
                              hipStream_t stream) {
    (void)in_sizes; (void)n_in; (void)out_size; (void)ws_size;
    const float* queries = (const float*)d_in[0];
    const float* key     = (const float*)d_in[1];
    const float* pos     = (const float*)d_in[2];
    const float* ipw     = (const float*)d_in[3];
    const float* ipb     = (const float*)d_in[4];
    const float* opw     = (const float*)d_in[5];
    const float* opb     = (const float*)d_in[6];
    float* out = (float*)d_out;

    unsigned short* us = (unsigned short*)d_ws;
    const size_t SZ = (size_t)2 * P * 256;      // 1,605,632 ushorts per [2][P][256]-ish buffer
    unsigned short* Qt = us;                    // [2][P][256]   queries^T
    unsigned short* Kt = us + SZ;               // [2][P][256]   key^T
    unsigned short* Qb = us + 2 * SZ;           // [2][8][P][32] Q heads
    unsigned short* Kb = us + 3 * SZ;           // [2][8][P][32] K delta
    unsigned short* Vb = us + 4 * SZ;           // [2][8][P][32] V delta
    unsigned short* Ot = us + 5 * SZ;           // [2][P][256]   attn delta out
    unsigned short* Wb = us + 6 * SZ;           // 1024x256 bf16 weights (ipw|opw)
    float* fc  = (float*)(us + 6 * SZ + 262144);
    float* vbc = fc;                            // 256
    float* obc = fc + 256;                      // 256

    hipLaunchKernelGGL(wconv_kernel, dim3(256), dim3(256), 0, stream, ipw, opw, Wb);
    hipLaunchKernelGGL(tconv_kernel, dim3(49, 4, 4), dim3(256), 0, stream, queries, key, Qt, Kt);
    hipLaunchKernelGGL(vb_kernel, dim3(16), dim3(256), 0, stream, ipw, ipb, pos, vbc);
    hipLaunchKernelGGL(ob_kernel, dim3(16), dim3(256), 0, stream, opw, opb, vbc, obc);
    hipLaunchKernelGGL(proj_mfma, dim3(49, 6, 2), dim3(256), 0, stream,
                       Wb, Qt, Kt, ipb, Qb, Kb, Vb);
    hipLaunchKernelGGL(attn_kernel, dim3(49, 8, 2), dim3(64), 0, stream, Qb, Kb, Vb, Ot);
    hipLaunchKernelGGL(outproj_mfma, dim3(49, 2, 2), dim3(256), 0, stream, Wb, Ot, obc, out);
}

// Round 3
// 126.534 us; speedup vs baseline: 1.8263x; 1.0023x over previous
//
#include <hip/hip_runtime.h>
#include <stdint.h>

#define HW 56
#define P 3136
#define C 256
#define CP (C*P)

typedef float  f32x4  __attribute__((ext_vector_type(4)));
typedef short  short8 __attribute__((ext_vector_type(8)));

// ---------------------------------------------------------------- helpers
__device__ __forceinline__ unsigned short f2bf(float f) {          // RNE fp32->bf16
    uint32_t u = __float_as_uint(f);
    uint32_t r = (u + 0x7fffu + ((u >> 16) & 1u)) >> 16;
    return (unsigned short)r;
}
__device__ __forceinline__ float bl(uint32_t u) { return __uint_as_float(u << 16); }
__device__ __forceinline__ float bh(uint32_t u) { return __uint_as_float(u & 0xffff0000u); }

__device__ __forceinline__ void gload16(const void* g, const void* l) {
    __builtin_amdgcn_global_load_lds(
        (const __attribute__((address_space(1))) uint32_t*)g,
        (__attribute__((address_space(3))) uint32_t*)l, 16, 0, 0);
}

// ---------------------------------------------------------------- prep: weights->bf16  +  vb
// blocks 0..255: convert ipw(768x256)|opw(256x256) fp32 -> bf16 Wb
// blocks 256..271: vb[r] = pe * rowsum(Wv[r]) + bv[r]
__global__ __launch_bounds__(256) void wconv_vb_kernel(const float* __restrict__ ipw,
                                                       const float* __restrict__ opw,
                                                       const float* __restrict__ ipb,
                                                       const float* __restrict__ pos,
                                                       unsigned short* __restrict__ Wb,
                                                       float* __restrict__ vbc) {
    int bx = blockIdx.x;
    if (bx < 256) {
        int i4 = bx * 256 + threadIdx.x;          // 65536 float4's
        const float4* src = (i4 < 49152) ? (const float4*)ipw : (const float4*)opw;
        int idx = (i4 < 49152) ? i4 : i4 - 49152;
        float4 v = src[idx];
        ((ushort4*)Wb)[i4] = make_ushort4(f2bf(v.x), f2bf(v.y), f2bf(v.z), f2bf(v.w));
    } else {
        int b = bx - 256;                          // 0..15
        int w = threadIdx.x >> 6, lane = threadIdx.x & 63;
        float pe = pos[0];
        #pragma unroll
        for (int i = 0; i < 4; ++i) {
            int r = b * 16 + w * 4 + i;
            const float* row = ipw + (size_t)(512 + r) * 256;
            float s = row[lane] + row[lane + 64] + row[lane + 128] + row[lane + 192];
            #pragma unroll
            for (int off = 32; off; off >>= 1) s += __shfl_xor(s, off);
            if (lane == 0) vbc[r] = fmaf(pe, s, ipb[512 + r]);
        }
    }
}

// ---------------------------------------------------------------- prep: transpose+convert activations
// X [C][P] fp32 (channel-major)  ->  Xt [P][C] bf16 (pixel-major)
__global__ __launch_bounds__(256) void tconv_kernel(const float* __restrict__ queries,
                                                    const float* __restrict__ key,
                                                    unsigned short* __restrict__ Qt,
                                                    unsigned short* __restrict__ Kt) {
    __shared__ float Ls[64][65];
    int t = threadIdx.x;
    int p0 = blockIdx.x * 64, ci0 = blockIdx.y * 64;
    int n = blockIdx.z & 1, which = blockIdx.z >> 1;
    const float* X = (which ? key : queries) + (size_t)n * CP;
    unsigned short* Xt = (which ? Kt : Qt) + (size_t)n * P * 256;

    int c = t & 63, r0 = t >> 6;
    #pragma unroll
    for (int rr = 0; rr < 16; ++rr) {
        int cil = r0 * 16 + rr;
        Ls[c][cil] = X[(size_t)(ci0 + cil) * P + p0 + c];
    }
    __syncthreads();
    int pl = t >> 2, cch = (t & 3) * 16;
    uint32_t us[8];
    #pragma unroll
    for (int j = 0; j < 8; ++j) {
        float lo = Ls[pl][cch + 2 * j], hi = Ls[pl][cch + 2 * j + 1];
        us[j] = (uint32_t)f2bf(lo) | ((uint32_t)f2bf(hi) << 16);
    }
    uint4* dst = (uint4*)(Xt + (size_t)(p0 + pl) * 256 + ci0 + cch);
    dst[0] = make_uint4(us[0], us[1], us[2], us[3]);
    dst[1] = make_uint4(us[4], us[5], us[6], us[7]);
}

// ---------------------------------------------------------------- MFMA GEMM core (unchanged, proven)
// A bf16 [*][256] row-major at co-tile start; B bf16 [P][256] p-major.
// Tile 128(co) x 64(p), BK=32, 4 waves (2x2), per-wave 64x32 -> acc[4][2] of 16x16.
__device__ __forceinline__ void gemm_core(const unsigned short* __restrict__ A,
                                          const unsigned short* __restrict__ B,
                                          int p0, unsigned short* As, unsigned short* Bs,
                                          f32x4 acc[4][2]) {
    int tid = threadIdx.x;
    int wid = __builtin_amdgcn_readfirstlane(tid >> 6);
    int lane = tid & 63;
    int wr = wid >> 1, wc = wid & 1;

    #pragma unroll
    for (int m = 0; m < 4; ++m)
        #pragma unroll
        for (int j = 0; j < 2; ++j) acc[m][j] = (f32x4){0.f, 0.f, 0.f, 0.f};

    for (int k0 = 0; k0 < 256; k0 += 32) {
        #pragma unroll
        for (int i = 0; i < 2; ++i) {
            int ch = i * 256 + (wid << 6) + lane;
            int row = ch >> 2;
            int g = (ch & 3) ^ ((row >> 1) & 3);
            gload16(A + (size_t)row * 256 + k0 + g * 8, (const char*)As + i * 4096 + wid * 1024);
        }
        {
            int ch = (wid << 6) + lane;
            int row = ch >> 2;
            int g = (ch & 3) ^ ((row >> 1) & 3);
            gload16(B + (size_t)(p0 + row) * 256 + k0 + g * 8, (const char*)Bs + wid * 1024);
        }
        __syncthreads();
        short8 af[4], bfr[2];
        #pragma unroll
        for (int m = 0; m < 4; ++m) {
            int col = (wr << 6) + m * 16 + (lane & 15);
            int phys = (lane >> 4) ^ ((col >> 1) & 3);
            af[m] = *(const short8*)((const char*)As + col * 64 + phys * 16);
        }
        #pragma unroll
        for (int j = 0; j < 2; ++j) {
            int pl = (wc << 5) + j * 16 + (lane & 15);
            int phys = (lane >> 4) ^ ((pl >> 1) & 3);
            bfr[j] = *(const short8*)((const char*)Bs + pl * 64 + phys * 16);
        }
        #pragma unroll
        for (int m = 0; m < 4; ++m)
            #pragma unroll
            for (int j = 0; j < 2; ++j)
                acc[m][j] = __builtin_amdgcn_mfma_f32_16x16x32_bf16(af[m], bfr[j], acc[m][j], 0, 0, 0);
        __syncthreads();
    }
}

// ---------------------------------------------------------------- proj: Q=Wq@queries+bq, Kd=Wk@key, Vd=Wv@key
// grid (49, 6, 2); output layout [n][h][p][32] bf16
__global__ __launch_bounds__(256) void proj_mfma(const unsigned short* __restrict__ Wb,
                                                 const unsigned short* __restrict__ Qt,
                                                 const unsigned short* __restrict__ Kt,
                                                 const float* __restrict__ ipb,
                                                 unsigned short* __restrict__ Qb,
                                                 unsigned short* __restrict__ Kb,
                                                 unsigned short* __restrict__ Vb) {
    __shared__ __align__(16) unsigned short As[4096];
    __shared__ __align__(16) unsigned short Bs[2048];
    int ty = blockIdx.y, n = blockIdx.z;
    int p0 = blockIdx.x * 64;
    int proj = ty >> 1;
    int co0 = ty * 128;
    const unsigned short* A = Wb + (size_t)co0 * 256;
    const unsigned short* B = (proj == 0 ? Qt : Kt) + (size_t)n * P * 256;
    unsigned short* outb = (proj == 0 ? Qb : (proj == 1 ? Kb : Vb)) + (size_t)n * 8 * P * 32;
    int col0 = (ty & 1) * 128;

    f32x4 acc[4][2];
    gemm_core(A, B, p0, As, Bs, acc);

    int lane = threadIdx.x & 63;
    int wid = threadIdx.x >> 6;
    int wr = wid >> 1, wc = wid & 1;
    #pragma unroll
    for (int m = 0; m < 4; ++m)
        #pragma unroll
        for (int j = 0; j < 2; ++j) {
            int col = col0 + (wr << 6) + m * 16 + (lane >> 4) * 4;
            int p   = p0 + (wc << 5) + j * 16 + (lane & 15);
            float v0 = acc[m][j][0], v1 = acc[m][j][1], v2 = acc[m][j][2], v3 = acc[m][j][3];
            if (proj == 0) {
                int cg = co0 + (wr << 6) + m * 16 + (lane >> 4) * 4;
                v0 += ipb[cg]; v1 += ipb[cg + 1]; v2 += ipb[cg + 2]; v3 += ipb[cg + 3];
            }
            int h = col >> 5, d = col & 31;
            ushort4 u = make_ushort4(f2bf(v0), f2bf(v1), f2bf(v2), f2bf(v3));
            *(ushort4*)(outb + ((size_t)(h * P + p)) * 32 + d) = u;
        }
}

// ---------------------------------------------------------------- attention (delta form, 4-wave tap split)
// block 256 = 4 waves over 64 pixels, one head. Phase 1: waves own tap ranges,
// store exp-weights in LDS. Phase 2: waves own 8-channel d-chunks of V-accum.
__constant__ const float kScale = 0.17677669529663687f;   // 1/sqrt(32)

template<int T0, int T1>
__device__ __forceinline__ void tap_range(const float* __restrict__ q,
                                          const unsigned short* __restrict__ Kbase,
                                          int p, int y, int x,
                                          float* __restrict__ ws_col, float& l) {
    #pragma unroll
    for (int t = T0; t < T1; ++t) {
        int dy = t / 7 - 3, dx = t % 7 - 3;
        int yy = y + dy, xx = x + dx;
        bool in = (yy >= 0) & (yy < HW) & (xx >= 0) & (xx < HW);
        int pnb = in ? (p + dy * HW + dx) : p;
        const uint4* kr = (const uint4*)(Kbase + (size_t)pnb * 32);
        float dot = 0.f;
        #pragma unroll
        for (int c = 0; c < 4; ++c) {
            uint4 u = kr[c];
            dot = fmaf(q[c*8+0], bl(u.x), dot); dot = fmaf(q[c*8+1], bh(u.x), dot);
            dot = fmaf(q[c*8+2], bl(u.y), dot); dot = fmaf(q[c*8+3], bh(u.y), dot);
            dot = fmaf(q[c*8+4], bl(u.z), dot); dot = fmaf(q[c*8+5], bh(u.z), dot);
            dot = fmaf(q[c*8+6], bl(u.w), dot); dot = fmaf(q[c*8+7], bh(u.w), dot);
        }
        float e = in ? __expf(dot * kScale) : 0.f;
        l += in ? e : 1.0f;
        ws_col[t * 64] = e;
    }
}

__global__ __launch_bounds__(256) void attn_kernel(const unsigned short* __restrict__ Qb,
                                                   const unsigned short* __restrict__ Kb,
                                                   const unsigned short* __restrict__ Vb,
                                                   unsigned short* __restrict__ Ot) {
    __shared__ float Ws[49][64];
    __shared__ float Lp[4][64];
    int tid = threadIdx.x;
    int lane = tid & 63, wave = tid >> 6;
    int p = blockIdx.x * 64 + lane;
    int h = blockIdx.y, n = blockIdx.z;
    int y = p / HW, x = p % HW;

    const unsigned short* Kbase = Kb + (size_t)(n * 8 + h) * P * 32;
    const unsigned short* Vbase = Vb + (size_t)(n * 8 + h) * P * 32;

    // Q into registers (each wave loads its own copy; L1-hit after first)
    const uint4* qr = (const uint4*)(Qb + ((size_t)((n * 8 + h) * P + p)) * 32);
    float q[32];
    #pragma unroll
    for (int c = 0; c < 4; ++c) {
        uint4 u = qr[c];
        q[c*8+0] = bl(u.x); q[c*8+1] = bh(u.x); q[c*8+2] = bl(u.y); q[c*8+3] = bh(u.y);
        q[c*8+4] = bl(u.z); q[c*8+5] = bh(u.z); q[c*8+6] = bl(u.w); q[c*8+7] = bh(u.w);
    }

    float l = 0.f;
    float* ws_col = &Ws[0][lane];
    if      (wave == 0) tap_range< 0, 13>(q, Kbase, p, y, x, ws_col, l);
    else if (wave == 1) tap_range<13, 25>(q, Kbase, p, y, x, ws_col, l);
    else if (wave == 2) tap_range<25, 37>(q, Kbase, p, y, x, ws_col, l);
    else                tap_range<37, 49>(q, Kbase, p, y, x, ws_col, l);
    Lp[wave][lane] = l;
    __syncthreads();

    float lt = Lp[0][lane] + Lp[1][lane] + Lp[2][lane] + Lp[3][lane];
    float inv = __builtin_amdgcn_rcpf(lt);

    // Phase 2: this wave accumulates V channels [d0, d0+8)
    int d0 = wave * 8;
    float o[8] = {0.f, 0.f, 0.f, 0.f, 0.f, 0.f, 0.f, 0.f};
    #pragma unroll
    for (int t = 0; t < 49; ++t) {
        int dy = t / 7 - 3, dx = t % 7 - 3;
        int yy = y + dy, xx = x + dx;
        bool in = (yy >= 0) & (yy < HW) & (xx >= 0) & (xx < HW);
        int pnb = in ? (p + dy * HW + dx) : p;
        float w = Ws[t][lane];                    // 0 for OOB taps
        uint4 u = *(const uint4*)(Vbase + (size_t)pnb * 32 + d0);
        o[0] = fmaf(w, bl(u.x), o[0]); o[1] = fmaf(w, bh(u.x), o[1]);
        o[2] = fmaf(w, bl(u.y), o[2]); o[3] = fmaf(w, bh(u.y), o[3]);
        o[4] = fmaf(w, bl(u.z), o[4]); o[5] = fmaf(w, bh(u.z), o[5]);
        o[6] = fmaf(w, bl(u.w), o[6]); o[7] = fmaf(w, bh(u.w), o[7]);
    }
    uint32_t us[4];
    #pragma unroll
    for (int j = 0; j < 4; ++j)
        us[j] = (uint32_t)f2bf(o[2*j] * inv) | ((uint32_t)f2bf(o[2*j+1] * inv) << 16);
    *(uint4*)(Ot + (size_t)(n * P + p) * 256 + h * 32 + d0) =
        make_uint4(us[0], us[1], us[2], us[3]);
}

// ---------------------------------------------------------------- out-proj: out = opw @ Od + (opw@vb+opb)
// grid (49, 2, 2); obc computed in-block (fp32-exact); output fp32 channel-major
__global__ __launch_bounds__(256) void outproj_mfma(const unsigned short* __restrict__ Wb,
                                                    const unsigned short* __restrict__ Ot,
                                                    const float* __restrict__ opw,
                                                    const float* __restrict__ opb,
                                                    const float* __restrict__ vbc,
                                                    float* __restrict__ out) {
    __shared__ __align__(16) unsigned short As[4096];
    __shared__ __align__(16) unsigned short Bs[2048];
    __shared__ float obc_s[128];
    int tid = threadIdx.x;
    int n = blockIdx.z;
    int p0 = blockIdx.x * 64;
    int co0 = blockIdx.y * 128;

    // obc for this co-tile: thread pair per row (half each), fp32 exact
    {
        int r = tid >> 1, half = tid & 1;
        const float* row = opw + (size_t)(co0 + r) * 256 + half * 128;
        const float* vh = vbc + half * 128;
        float s = 0.f;
        #pragma unroll 8
        for (int i = 0; i < 128; ++i) s = fmaf(row[i], vh[i], s);
        s += __shfl_xor(s, 1);
        if (half == 0) obc_s[r] = s + opb[co0 + r];
    }

    const unsigned short* A = Wb + (size_t)(768 + co0) * 256;
    const unsigned short* B = Ot + (size_t)n * P * 256;
    f32x4 acc[4][2];
    gemm_core(A, B, p0, As, Bs, acc);   // internal barriers order obc_s before epilogue

    int lane = tid & 63;
    int wid = tid >> 6;
    int wr = wid >> 1, wc = wid & 1;
    #pragma unroll
    for (int m = 0; m < 4; ++m)
        #pragma unroll
        for (int j = 0; j < 2; ++j) {
            int col = (wr << 6) + m * 16 + (lane >> 4) * 4;   // co within tile
            int p  = p0 + (wc << 5) + j * 16 + (lane & 15);
            #pragma unroll
            for (int i = 0; i < 4; ++i)
                out[(size_t)n * CP + (size_t)(co0 + col + i) * P + p] = acc[m][j][i] + obc_s[col + i];
        }
}

// ----------------------------------------------------------------
extern "C" void kernel_launch(void* const* d_in, const int* in_sizes, int n_in,
                              void* d_out, int out_size, void* d_ws, size_t ws_size,
                              hipStream_t stream) {
    (void)in_sizes; (void)n_in; (void)out_size; (void)ws_size;
    const float* queries = (const float*)d_in[0];
    const float* key     = (const float*)d_in[1];
    const float* pos     = (const float*)d_in[2];
    const float* ipw     = (const float*)d_in[3];
    const float* ipb     = (const float*)d_in[4];
    const float* opw     = (const float*)d_in[5];
    const float* opb     = (const float*)d_in[6];
    float* out = (float*)d_out;

    unsigned short* us = (unsigned short*)d_ws;
    const size_t SZ = (size_t)2 * P * 256;
    unsigned short* Qt = us;                    // [2][P][256]   queries^T bf16
    unsigned short* Kt = us + SZ;               // [2][P][256]   key^T bf16
    unsigned short* Qb = us + 2 * SZ;           // [2][8][P][32] Q heads
    unsigned short* Kb = us + 3 * SZ;           // [2][8][P][32] K delta
    unsigned short* Vb = us + 4 * SZ;           // [2][8][P][32] V delta
    unsigned short* Ot = us + 5 * SZ;           // [2][P][256]   attn delta out
    unsigned short* Wb = us + 6 * SZ;           // 1024x256 bf16 weights (ipw|opw)
    float* vbc = (float*)(us + 6 * SZ + 262144); // 256 floats

    hipLaunchKernelGGL(wconv_vb_kernel, dim3(272), dim3(256), 0, stream,
                       ipw, opw, ipb, pos, Wb, vbc);
    hipLaunchKernelGGL(tconv_kernel, dim3(49, 4, 4), dim3(256), 0, stream,
                       queries, key, Qt, Kt);
    hipLaunchKernelGGL(proj_mfma, dim3(49, 6, 2), dim3(256), 0, stream,
                       Wb, Qt, Kt, ipb, Qb, Kb, Vb);
    hipLaunchKernelGGL(attn_kernel, dim3(49, 8, 2), dim3(256), 0, stream, Qb, Kb, Vb, Ot);
    hipLaunchKernelGGL(outproj_mfma, dim3(49, 2, 2), dim3(256), 0, stream,
                       Wb, Ot, opw, opb, vbc, out);
}

// Round 4
// 121.683 us; speedup vs baseline: 1.8991x; 1.0399x over previous
//
#include <hip/hip_runtime.h>
#include <stdint.h>

#define HW 56
#define P 3136
#define C 256
#define CP (C*P)

typedef float  f32x4  __attribute__((ext_vector_type(4)));
typedef short  short8 __attribute__((ext_vector_type(8)));

// ---------------------------------------------------------------- helpers
__device__ __forceinline__ unsigned short f2bf(float f) {          // RNE fp32->bf16
    uint32_t u = __float_as_uint(f);
    uint32_t r = (u + 0x7fffu + ((u >> 16) & 1u)) >> 16;
    return (unsigned short)r;
}
__device__ __forceinline__ float bl(uint32_t u) { return __uint_as_float(u << 16); }
__device__ __forceinline__ float bh(uint32_t u) { return __uint_as_float(u & 0xffff0000u); }

__device__ __forceinline__ void gload16(const void* g, const void* l) {
    __builtin_amdgcn_global_load_lds(
        (const __attribute__((address_space(1))) uint32_t*)g,
        (__attribute__((address_space(3))) uint32_t*)l, 16, 0, 0);
}

// ---------------------------------------------------------------- prep (fused):
// blocks [0,256):    ipw|opw fp32 -> bf16 Wb
// blocks [256,272):  vb[r] = pe * rowsum(Wv[r]) + bv[r]
// blocks [272,1056): transpose+convert queries/key [C][P] fp32 -> [P][C] bf16
__global__ __launch_bounds__(256) void prep_kernel(const float* __restrict__ queries,
                                                   const float* __restrict__ key,
                                                   const float* __restrict__ ipw,
                                                   const float* __restrict__ opw,
                                                   const float* __restrict__ ipb,
                                                   const float* __restrict__ pos,
                                                   unsigned short* __restrict__ Wb,
                                                   float* __restrict__ vbc,
                                                   unsigned short* __restrict__ Qt,
                                                   unsigned short* __restrict__ Kt) {
    __shared__ float Ls[64][65];
    int bx = blockIdx.x;
    if (bx < 256) {
        int i4 = bx * 256 + threadIdx.x;          // 65536 float4's
        const float4* src = (i4 < 49152) ? (const float4*)ipw : (const float4*)opw;
        int idx = (i4 < 49152) ? i4 : i4 - 49152;
        float4 v = src[idx];
        ((ushort4*)Wb)[i4] = make_ushort4(f2bf(v.x), f2bf(v.y), f2bf(v.z), f2bf(v.w));
    } else if (bx < 272) {
        int b = bx - 256;                          // 0..15
        int w = threadIdx.x >> 6, lane = threadIdx.x & 63;
        float pe = pos[0];
        #pragma unroll
        for (int i = 0; i < 4; ++i) {
            int r = b * 16 + w * 4 + i;
            const float* row = ipw + (size_t)(512 + r) * 256;
            float s = row[lane] + row[lane + 64] + row[lane + 128] + row[lane + 192];
            #pragma unroll
            for (int off = 32; off; off >>= 1) s += __shfl_xor(s, off);
            if (lane == 0) vbc[r] = fmaf(pe, s, ipb[512 + r]);
        }
    } else {
        int idx = bx - 272;                        // 0..783  (49 x 4 x 4)
        int t = threadIdx.x;
        int p0 = (idx % 49) * 64, ci0 = ((idx / 49) & 3) * 64;
        int z = idx / 196;
        int n = z & 1, which = z >> 1;
        const float* X = (which ? key : queries) + (size_t)n * CP;
        unsigned short* Xt = (which ? Kt : Qt) + (size_t)n * P * 256;

        int c = t & 63, r0 = t >> 6;
        #pragma unroll
        for (int rr = 0; rr < 16; ++rr) {
            int cil = r0 * 16 + rr;
            Ls[c][cil] = X[(size_t)(ci0 + cil) * P + p0 + c];
        }
        __syncthreads();
        int pl = t >> 2, cch = (t & 3) * 16;
        uint32_t us[8];
        #pragma unroll
        for (int j = 0; j < 8; ++j) {
            float lo = Ls[pl][cch + 2 * j], hi = Ls[pl][cch + 2 * j + 1];
            us[j] = (uint32_t)f2bf(lo) | ((uint32_t)f2bf(hi) << 16);
        }
        uint4* dst = (uint4*)(Xt + (size_t)(p0 + pl) * 256 + ci0 + cch);
        dst[0] = make_uint4(us[0], us[1], us[2], us[3]);
        dst[1] = make_uint4(us[4], us[5], us[6], us[7]);
    }
}

// ---------------------------------------------------------------- MFMA GEMM core, BK=64
// A bf16 [rows][256] row-major (rows = MR*32); B bf16 [P][256] p-major, 64-wide p-tile.
// 4 waves (2x2): per-wave (MR*16)co x 32p; 4 K-steps of 64.
// LDS rows are 128 B = 8 chunks of 16 B; chunk swizzle: phys = logical ^ (row & 7).
template<int MR>
__device__ __forceinline__ void gemm_core64(const unsigned short* __restrict__ A,
                                            const unsigned short* __restrict__ B,
                                            int p0, unsigned short* As, unsigned short* Bs,
                                            f32x4 acc[MR][2]) {
    int tid = threadIdx.x;
    int wid = __builtin_amdgcn_readfirstlane(tid >> 6);
    int lane = tid & 63;
    int wr = wid >> 1, wc = wid & 1;

    #pragma unroll
    for (int m = 0; m < MR; ++m)
        #pragma unroll
        for (int j = 0; j < 2; ++j) acc[m][j] = (f32x4){0.f, 0.f, 0.f, 0.f};

    for (int k0 = 0; k0 < 256; k0 += 64) {
        // stage A: MR*256 chunks of 16B (pre-swizzled global source, linear LDS dest)
        #pragma unroll
        for (int i = 0; i < MR; ++i) {
            int ch = i * 256 + (wid << 6) + lane;
            int row = ch >> 3;
            int g = (ch & 7) ^ (row & 7);
            gload16(A + (size_t)row * 256 + k0 + g * 8,
                    (const char*)As + (i * 256 + (wid << 6)) * 16);
        }
        // stage B: 512 chunks
        #pragma unroll
        for (int i = 0; i < 2; ++i) {
            int ch = i * 256 + (wid << 6) + lane;
            int row = ch >> 3;
            int g = (ch & 7) ^ (row & 7);
            gload16(B + (size_t)(p0 + row) * 256 + k0 + g * 8,
                    (const char*)Bs + (i * 256 + (wid << 6)) * 16);
        }
        __syncthreads();
        short8 af[MR][2], bfr[2][2];
        #pragma unroll
        for (int m = 0; m < MR; ++m)
            #pragma unroll
            for (int ks = 0; ks < 2; ++ks) {
                int col = wr * (MR * 16) + m * 16 + (lane & 15);
                int phys = (ks * 4 + (lane >> 4)) ^ (col & 7);
                af[m][ks] = *(const short8*)((const char*)As + col * 128 + phys * 16);
            }
        #pragma unroll
        for (int j = 0; j < 2; ++j)
            #pragma unroll
            for (int ks = 0; ks < 2; ++ks) {
                int pl = (wc << 5) + j * 16 + (lane & 15);
                int phys = (ks * 4 + (lane >> 4)) ^ (pl & 7);
                bfr[j][ks] = *(const short8*)((const char*)Bs + pl * 128 + phys * 16);
            }
        #pragma unroll
        for (int m = 0; m < MR; ++m)
            #pragma unroll
            for (int j = 0; j < 2; ++j)
                #pragma unroll
                for (int ks = 0; ks < 2; ++ks)
                    acc[m][j] = __builtin_amdgcn_mfma_f32_16x16x32_bf16(af[m][ks], bfr[j][ks], acc[m][j], 0, 0, 0);
        __syncthreads();
    }
}

// ---------------------------------------------------------------- proj: Q=Wq@queries+bq, Kd=Wk@key, Vd=Wv@key
// grid (49, 6, 2); tile 128co x 64p; output layout [n][h][p][32] bf16
__global__ __launch_bounds__(256) void proj_mfma(const unsigned short* __restrict__ Wb,
                                                 const unsigned short* __restrict__ Qt,
                                                 const unsigned short* __restrict__ Kt,
                                                 const float* __restrict__ ipb,
                                                 unsigned short* __restrict__ Qb,
                                                 unsigned short* __restrict__ Kb,
                                                 unsigned short* __restrict__ Vb) {
    __shared__ __align__(16) unsigned short As[8192];   // 128 x 64 bf16
    __shared__ __align__(16) unsigned short Bs[4096];   // 64 x 64 bf16
    int ty = blockIdx.y, n = blockIdx.z;
    int p0 = blockIdx.x * 64;
    int proj = ty >> 1;
    int co0 = ty * 128;
    const unsigned short* A = Wb + (size_t)co0 * 256;
    const unsigned short* B = (proj == 0 ? Qt : Kt) + (size_t)n * P * 256;
    unsigned short* outb = (proj == 0 ? Qb : (proj == 1 ? Kb : Vb)) + (size_t)n * 8 * P * 32;
    int col0 = (ty & 1) * 128;

    f32x4 acc[4][2];
    gemm_core64<4>(A, B, p0, As, Bs, acc);

    int lane = threadIdx.x & 63;
    int wid = threadIdx.x >> 6;
    int wr = wid >> 1, wc = wid & 1;
    #pragma unroll
    for (int m = 0; m < 4; ++m)
        #pragma unroll
        for (int j = 0; j < 2; ++j) {
            int col = col0 + (wr << 6) + m * 16 + (lane >> 4) * 4;
            int p   = p0 + (wc << 5) + j * 16 + (lane & 15);
            float v0 = acc[m][j][0], v1 = acc[m][j][1], v2 = acc[m][j][2], v3 = acc[m][j][3];
            if (proj == 0) {
                int cg = co0 + (wr << 6) + m * 16 + (lane >> 4) * 4;
                v0 += ipb[cg]; v1 += ipb[cg + 1]; v2 += ipb[cg + 2]; v3 += ipb[cg + 3];
            }
            int h = col >> 5, d = col & 31;
            ushort4 u = make_ushort4(f2bf(v0), f2bf(v1), f2bf(v2), f2bf(v3));
            *(ushort4*)(outb + ((size_t)(h * P + p)) * 32 + d) = u;
        }
}

// ---------------------------------------------------------------- attention (unchanged, proven)
__constant__ const float kScale = 0.17677669529663687f;   // 1/sqrt(32)

template<int T0, int T1>
__device__ __forceinline__ void tap_range(const float* __restrict__ q,
                                          const unsigned short* __restrict__ Kbase,
                                          int p, int y, int x,
                                          float* __restrict__ ws_col, float& l) {
    #pragma unroll
    for (int t = T0; t < T1; ++t) {
        int dy = t / 7 - 3, dx = t % 7 - 3;
        int yy = y + dy, xx = x + dx;
        bool in = (yy >= 0) & (yy < HW) & (xx >= 0) & (xx < HW);
        int pnb = in ? (p + dy * HW + dx) : p;
        const uint4* kr = (const uint4*)(Kbase + (size_t)pnb * 32);
        float dot = 0.f;
        #pragma unroll
        for (int c = 0; c < 4; ++c) {
            uint4 u = kr[c];
            dot = fmaf(q[c*8+0], bl(u.x), dot); dot = fmaf(q[c*8+1], bh(u.x), dot);
            dot = fmaf(q[c*8+2], bl(u.y), dot); dot = fmaf(q[c*8+3], bh(u.y), dot);
            dot = fmaf(q[c*8+4], bl(u.z), dot); dot = fmaf(q[c*8+5], bh(u.z), dot);
            dot = fmaf(q[c*8+6], bl(u.w), dot); dot = fmaf(q[c*8+7], bh(u.w), dot);
        }
        float e = in ? __expf(dot * kScale) : 0.f;
        l += in ? e : 1.0f;
        ws_col[t * 64] = e;
    }
}

__global__ __launch_bounds__(256) void attn_kernel(const unsigned short* __restrict__ Qb,
                                                   const unsigned short* __restrict__ Kb,
                                                   const unsigned short* __restrict__ Vb,
                                                   unsigned short* __restrict__ Ot) {
    __shared__ float Ws[49][64];
    __shared__ float Lp[4][64];
    int tid = threadIdx.x;
    int lane = tid & 63, wave = tid >> 6;
    int p = blockIdx.x * 64 + lane;
    int h = blockIdx.y, n = blockIdx.z;
    int y = p / HW, x = p % HW;

    const unsigned short* Kbase = Kb + (size_t)(n * 8 + h) * P * 32;
    const unsigned short* Vbase = Vb + (size_t)(n * 8 + h) * P * 32;

    const uint4* qr = (const uint4*)(Qb + ((size_t)((n * 8 + h) * P + p)) * 32);
    float q[32];
    #pragma unroll
    for (int c = 0; c < 4; ++c) {
        uint4 u = qr[c];
        q[c*8+0] = bl(u.x); q[c*8+1] = bh(u.x); q[c*8+2] = bl(u.y); q[c*8+3] = bh(u.y);
        q[c*8+4] = bl(u.z); q[c*8+5] = bh(u.z); q[c*8+6] = bl(u.w); q[c*8+7] = bh(u.w);
    }

    float l = 0.f;
    float* ws_col = &Ws[0][lane];
    if      (wave == 0) tap_range< 0, 13>(q, Kbase, p, y, x, ws_col, l);
    else if (wave == 1) tap_range<13, 25>(q, Kbase, p, y, x, ws_col, l);
    else if (wave == 2) tap_range<25, 37>(q, Kbase, p, y, x, ws_col, l);
    else                tap_range<37, 49>(q, Kbase, p, y, x, ws_col, l);
    Lp[wave][lane] = l;
    __syncthreads();

    float lt = Lp[0][lane] + Lp[1][lane] + Lp[2][lane] + Lp[3][lane];
    float inv = __builtin_amdgcn_rcpf(lt);

    int d0 = wave * 8;
    float o[8] = {0.f, 0.f, 0.f, 0.f, 0.f, 0.f, 0.f, 0.f};
    #pragma unroll
    for (int t = 0; t < 49; ++t) {
        int dy = t / 7 - 3, dx = t % 7 - 3;
        int yy = y + dy, xx = x + dx;
        bool in = (yy >= 0) & (yy < HW) & (xx >= 0) & (xx < HW);
        int pnb = in ? (p + dy * HW + dx) : p;
        float w = Ws[t][lane];
        uint4 u = *(const uint4*)(Vbase + (size_t)pnb * 32 + d0);
        o[0] = fmaf(w, bl(u.x), o[0]); o[1] = fmaf(w, bh(u.x), o[1]);
        o[2] = fmaf(w, bl(u.y), o[2]); o[3] = fmaf(w, bh(u.y), o[3]);
        o[4] = fmaf(w, bl(u.z), o[4]); o[5] = fmaf(w, bh(u.z), o[5]);
        o[6] = fmaf(w, bl(u.w), o[6]); o[7] = fmaf(w, bh(u.w), o[7]);
    }
    uint32_t us[4];
    #pragma unroll
    for (int j = 0; j < 4; ++j)
        us[j] = (uint32_t)f2bf(o[2*j] * inv) | ((uint32_t)f2bf(o[2*j+1] * inv) << 16);
    *(uint4*)(Ot + (size_t)(n * P + p) * 256 + h * 32 + d0) =
        make_uint4(us[0], us[1], us[2], us[3]);
}

// ---------------------------------------------------------------- out-proj: out = opw @ Od + (opw@vb+opb)
// grid (49, 4, 2); tile 64co x 64p (2x occupancy); obc in-block fp32-exact.
__global__ __launch_bounds__(256) void outproj_mfma(const unsigned short* __restrict__ Wb,
                                                    const unsigned short* __restrict__ Ot,
                                                    const float* __restrict__ opw,
                                                    const float* __restrict__ opb,
                                                    const float* __restrict__ vbc,
                                                    float* __restrict__ out) {
    __shared__ __align__(16) unsigned short As[4096];   // 64 x 64 bf16
    __shared__ __align__(16) unsigned short Bs[4096];   // 64 x 64 bf16
    __shared__ float obc_s[64];
    int tid = threadIdx.x;
    int n = blockIdx.z;
    int p0 = blockIdx.x * 64;
    int co0 = blockIdx.y * 64;

    // obc for this co-tile: 4 lanes per row, 64-elem quarter each, fp32 exact
    {
        int r = tid >> 2, qq = tid & 3;
        const float* row = opw + (size_t)(co0 + r) * 256 + qq * 64;
        const float* vh = vbc + qq * 64;
        float s = 0.f;
        #pragma unroll 8
        for (int i = 0; i < 64; ++i) s = fmaf(row[i], vh[i], s);
        s += __shfl_xor(s, 1);
        s += __shfl_xor(s, 2);
        if (qq == 0) obc_s[r] = s + opb[co0 + r];
    }

    const unsigned short* A = Wb + (size_t)(768 + co0) * 256;
    const unsigned short* B = Ot + (size_t)n * P * 256;
    f32x4 acc[2][2];
    gemm_core64<2>(A, B, p0, As, Bs, acc);   // internal barriers order obc_s before epilogue

    int lane = tid & 63;
    int wid = tid >> 6;
    int wr = wid >> 1, wc = wid & 1;
    #pragma unroll
    for (int m = 0; m < 2; ++m)
        #pragma unroll
        for (int j = 0; j < 2; ++j) {
            int col = (wr << 5) + m * 16 + (lane >> 4) * 4;   // co within 64-tile
            int p  = p0 + (wc << 5) + j * 16 + (lane & 15);
            #pragma unroll
            for (int i = 0; i < 4; ++i)
                out[(size_t)n * CP + (size_t)(co0 + col + i) * P + p] = acc[m][j][i] + obc_s[col + i];
        }
}

// ----------------------------------------------------------------
extern "C" void kernel_launch(void* const* d_in, const int* in_sizes, int n_in,
                              void* d_out, int out_size, void* d_ws, size_t ws_size,
                              hipStream_t stream) {
    (void)in_sizes; (void)n_in; (void)out_size; (void)ws_size;
    const float* queries = (const float*)d_in[0];
    const float* key     = (const float*)d_in[1];
    const float* pos     = (const float*)d_in[2];
    const float* ipw     = (const float*)d_in[3];
    const float* ipb     = (const float*)d_in[4];
    const float* opw     = (const float*)d_in[5];
    const float* opb     = (const float*)d_in[6];
    float* out = (float*)d_out;

    unsigned short* us = (unsigned short*)d_ws;
    const size_t SZ = (size_t)2 * P * 256;
    unsigned short* Qt = us;                    // [2][P][256]   queries^T bf16
    unsigned short* Kt = us + SZ;               // [2][P][256]   key^T bf16
    unsigned short* Qb = us + 2 * SZ;           // [2][8][P][32] Q heads
    unsigned short* Kb = us + 3 * SZ;           // [2][8][P][32] K delta
    unsigned short* Vb = us + 4 * SZ;           // [2][8][P][32] V delta
    unsigned short* Ot = us + 5 * SZ;           // [2][P][256]   attn delta out
    unsigned short* Wb = us + 6 * SZ;           // 1024x256 bf16 weights (ipw|opw)
    float* vbc = (float*)(us + 6 * SZ + 262144); // 256 floats

    hipLaunchKernelGGL(prep_kernel, dim3(1056), dim3(256), 0, stream,
                       queries, key, ipw, opw, ipb, pos, Wb, vbc, Qt, Kt);
    hipLaunchKernelGGL(proj_mfma, dim3(49, 6, 2), dim3(256), 0, stream,
                       Wb, Qt, Kt, ipb, Qb, Kb, Vb);
    hipLaunchKernelGGL(attn_kernel, dim3(49, 8, 2), dim3(256), 0, stream, Qb, Kb, Vb, Ot);
    hipLaunchKernelGGL(outproj_mfma, dim3(49, 4, 2), dim3(256), 0, stream,
                       Wb, Ot, opw, opb, vbc, out);
}